// Round 20
// baseline (98.298 us; speedup 1.0000x reference)
//
#include <hip/hip_runtime.h>

// AdaptiveConv: out[b,c,h,w] = sum_{idx<25} x[b,c,h+idx/5, w+idx%5] * kernel[b,idx,h,w]
// Shapes: x (8,64,260,260) f32, kernel (8,25,256,256) f32, out (8,64,256,256) f32.
//
// R20: the ONE invariant across every plateau variant (65-67us, 7 falsified
// levers) is __builtin_nontemporal_store for the 131MB output — adopted in R3,
// never A/B'd. Measured write rate = 131MB/66us = 1.98 TB/s: plausibly the
// nt-store (L2-bypass, no write-combining) HBM ceiling. The 6.3 TB/s ubench
// was a normal copy THROUGH L2. This round = R11 (best timed, 64.9us) with
// plain stores — single-variable A/B on the store path.
// Pre-commit: flat 64-68us exonerates stores -> revert to R11, call ROOFLINE.

constexpr int K  = 5;
constexpr int B  = 8;
constexpr int C  = 64;
constexpr int H  = 256;
constexpr int W  = 256;
constexpr int HX = H + K - 1;   // 260
constexpr int WX = W + K - 1;   // 260

constexpr int CH  = 4;          // channels per thread (acc blocking)
constexpr int NCG = C / CH;     // 16 channel groups
constexpr int HPB = 4;          // output rows per block (one per 64-lane slice)
constexpr int NHB = H / HPB;    // 64 h-blocks
constexpr int NWG = NHB * B * NCG;  // 8192 blocks

constexpr int XROWS      = HPB + K - 1;      // 8 x-rows per block
constexpr int CH_FLOATS  = XROWS * WX;       // 2080 floats per channel
constexpr int LDS_FLOATS = CH * CH_FLOATS;   // 8320 floats = 33,280 B

typedef float f4 __attribute__((ext_vector_type(4)));

__global__ __launch_bounds__(256, 4)
void adaptive_conv_kernel(const float* __restrict__ x,
                          const float* __restrict__ kern,
                          float* __restrict__ out) {
    __shared__ float xs[LDS_FLOATS];

    // XCD-aware swizzle (bijective: NWG % 8 == 0); cg fastest so the 16 blocks
    // sharing one kern tile run consecutively on one XCD (R8, FETCH-verified).
    const int k    = blockIdx.x;
    const int orig = (k & 7) * (NWG / 8) + (k >> 3);
    const int cg   = orig & (NCG - 1);          // channel group (fastest)
    const int hblk = (orig >> 4) & (NHB - 1);   // h-block
    const int b    = orig >> 10;                // batch (slowest)

    const int tid  = threadIdx.x;
    const int lane = tid & 63;               // lane within wave; wave spans full W
    const int wv   = tid >> 6;               // 0..3: wave id = row slice
    const int w0   = lane * 4;               // 4 adjacent output columns (16B aligned)
    const int h    = hblk * HPB + wv;        // output row
    const int c0   = cg * CH;                // channel base

    const size_t xplane = (size_t)HX * WX;
    const float* kb = kern + (size_t)b * (K * K * H * W) + (size_t)h * W + w0;

    // ---- stage x[b, c0:c0+4, h0:h0+8, 0:260] -> LDS (33.3 KB, once) ----
    // Wave wv stages channel wv: 8 full-wave f4 sweeps + an 8-lane tail.
    {
        const float* src = x + ((size_t)b * C + c0 + wv) * xplane
                             + (size_t)(hblk * HPB) * WX;
        float* dst = &xs[wv * CH_FLOATS];
        #pragma unroll
        for (int t = 0; t < 8; ++t) {
            f4 v = *(const f4*)(src + t * 256 + lane * 4);
            *(f4*)(dst + t * 256 + lane * 4) = v;
        }
        if (lane < 8) {
            f4 v = *(const f4*)(src + 2048 + lane * 4);
            *(f4*)(dst + 2048 + lane * 4) = v;
        }
    }

    // Tap row 0 issued before the barrier (hides under the staging drain).
    f4 tcur[K], tnxt[K];
    #pragma unroll
    for (int j = 0; j < K; ++j) {
        tcur[j] = *(const f4*)(kb + (size_t)j * (H * W));
    }

    __syncthreads();

    f4 acc[CH];
    #pragma unroll
    for (int ch = 0; ch < CH; ++ch) acc[ch] = (f4)0.0f;

    #pragma unroll
    for (int i = 0; i < K; ++i) {
        if (i + 1 < K) {
            #pragma unroll
            for (int j = 0; j < K; ++j) {
                tnxt[j] = *(const f4*)(kb + (size_t)((i + 1) * K + j) * (H * W));
            }
        }

        #pragma unroll
        for (int ch = 0; ch < CH; ++ch) {
            // x row segment from LDS: cols w0..w0+7 of x-row (wv+i).
            // byte addr = 16*lane + const -> sequential 16B/lane, conflict-free.
            const float* xr = &xs[ch * CH_FLOATS + (wv + i) * WX + w0];
            f4 xa  = *(const f4*)(xr);
            f4 xcv = *(const f4*)(xr + 4);
            float xsg[8] = {xa.x, xa.y, xa.z, xa.w, xcv.x, xcv.y, xcv.z, xcv.w};

            #pragma unroll
            for (int j = 0; j < K; ++j) {      // static indices only (rule #20)
                acc[ch].x = fmaf(xsg[j + 0], tcur[j].x, acc[ch].x);
                acc[ch].y = fmaf(xsg[j + 1], tcur[j].y, acc[ch].y);
                acc[ch].z = fmaf(xsg[j + 2], tcur[j].z, acc[ch].z);
                acc[ch].w = fmaf(xsg[j + 3], tcur[j].w, acc[ch].w);
            }
        }

        if (i + 1 < K) {
            #pragma unroll
            for (int j = 0; j < K; ++j) tcur[j] = tnxt[j];
        }
    }

    float* ob = out + ((size_t)b * C + c0) * (H * W) + (size_t)h * W + w0;
    #pragma unroll
    for (int ch = 0; ch < CH; ++ch) {
        // R20 single-variable change: PLAIN store (through L2, write-combined)
        // instead of nontemporal. Theory: nt-stores stream to HBM at ~2 TB/s
        // = 131MB/66us = the plateau; L2-routed writes should sustain ~2x.
        *(f4*)(ob + (size_t)ch * (H * W)) = acc[ch];
    }
}

extern "C" void kernel_launch(void* const* d_in, const int* in_sizes, int n_in,
                              void* d_out, int out_size, void* d_ws, size_t ws_size,
                              hipStream_t stream) {
    const float* x    = (const float*)d_in[0];
    const float* kern = (const float*)d_in[1];
    float*       out  = (float*)d_out;

    dim3 grid(NWG);      // 8192 blocks, 1D; decode + swizzle in-kernel
    dim3 block(256);     // 4 row-slices x 64 lanes
    adaptive_conv_kernel<<<grid, block, 0, stream>>>(x, kern, out);
}

// Round 21
// 65.449 us; speedup vs baseline: 1.5019x; 1.5019x over previous
//
#include <hip/hip_runtime.h>

// AdaptiveConv: out[b,c,h,w] = sum_{idx<25} x[b,c,h+idx/5, w+idx%5] * kernel[b,idx,h,w]
// Shapes: x (8,64,260,260) f32, kernel (8,25,256,256) f32, out (8,64,256,256) f32.
//
// R21 = REVERT to R11 (best timed: 64.9us), after the R20 A/B proved nt-stores
// are a 1.5x WIN in the timed regime (they keep the 131MB output stream out of
// L3, so x+kern stay resident across graph replays; plain stores evict them ->
// 98us). Ledger of falsified levers (9 single-variable experiments): occupancy
// 20/42/50% flat; tap traffic 2x flat; tap prefetch sunk by RA (x2); asm pins
// sunk/spilled (x3); intra-block ping-pong -10%; LDS-reads/output -40% -> -12%;
// vmem-instr -38% flat; plain stores -50%. Every pipe term moved 1.4-2x alone,
// total invariant at ~65us => structural plateau of the L3-resident strategy.
//
// Structure: thread = 4 cols x 1 row x 4 ch (acc[4] f4); block = 4 waves, one
// output row each, full W=256; x tile (4ch x 8rows x 260 = 33.3KB) in LDS;
// taps streamed from L2 (XCD swizzle makes 16 cg-sharers consecutive per XCD);
// depth-1 tap pipeline (RA sinks it at VGPR=64 — harmless); nt f4 stores.

constexpr int K  = 5;
constexpr int B  = 8;
constexpr int C  = 64;
constexpr int H  = 256;
constexpr int W  = 256;
constexpr int HX = H + K - 1;   // 260
constexpr int WX = W + K - 1;   // 260

constexpr int CH  = 4;          // channels per thread (acc blocking)
constexpr int NCG = C / CH;     // 16 channel groups
constexpr int HPB = 4;          // output rows per block (one per 64-lane slice)
constexpr int NHB = H / HPB;    // 64 h-blocks
constexpr int NWG = NHB * B * NCG;  // 8192 blocks

constexpr int XROWS      = HPB + K - 1;      // 8 x-rows per block
constexpr int CH_FLOATS  = XROWS * WX;       // 2080 floats per channel
constexpr int LDS_FLOATS = CH * CH_FLOATS;   // 8320 floats = 33,280 B

typedef float f4 __attribute__((ext_vector_type(4)));

__global__ __launch_bounds__(256, 4)
void adaptive_conv_kernel(const float* __restrict__ x,
                          const float* __restrict__ kern,
                          float* __restrict__ out) {
    __shared__ float xs[LDS_FLOATS];

    // XCD-aware swizzle (bijective: NWG % 8 == 0); cg fastest so the 16 blocks
    // sharing one kern tile run consecutively on one XCD (R8, FETCH-verified:
    // 472 -> 93 MB).
    const int k    = blockIdx.x;
    const int orig = (k & 7) * (NWG / 8) + (k >> 3);
    const int cg   = orig & (NCG - 1);          // channel group (fastest)
    const int hblk = (orig >> 4) & (NHB - 1);   // h-block
    const int b    = orig >> 10;                // batch (slowest)

    const int tid  = threadIdx.x;
    const int lane = tid & 63;               // lane within wave; wave spans full W
    const int wv   = tid >> 6;               // 0..3: wave id = row slice
    const int w0   = lane * 4;               // 4 adjacent output columns (16B aligned)
    const int h    = hblk * HPB + wv;        // output row
    const int c0   = cg * CH;                // channel base

    const size_t xplane = (size_t)HX * WX;
    const float* kb = kern + (size_t)b * (K * K * H * W) + (size_t)h * W + w0;

    // ---- stage x[b, c0:c0+4, h0:h0+8, 0:260] -> LDS (33.3 KB, once) ----
    // Wave wv stages channel wv: 8 full-wave f4 sweeps + an 8-lane tail.
    // Coalesced, sequential 16B/lane: conflict-free.
    {
        const float* src = x + ((size_t)b * C + c0 + wv) * xplane
                             + (size_t)(hblk * HPB) * WX;
        float* dst = &xs[wv * CH_FLOATS];
        #pragma unroll
        for (int t = 0; t < 8; ++t) {
            f4 v = *(const f4*)(src + t * 256 + lane * 4);
            *(f4*)(dst + t * 256 + lane * 4) = v;
        }
        if (lane < 8) {
            f4 v = *(const f4*)(src + 2048 + lane * 4);
            *(f4*)(dst + 2048 + lane * 4) = v;
        }
    }

    // Tap row 0 issued before the barrier (hides under the staging drain).
    f4 tcur[K], tnxt[K];
    #pragma unroll
    for (int j = 0; j < K; ++j) {
        tcur[j] = *(const f4*)(kb + (size_t)j * (H * W));
    }

    __syncthreads();

    f4 acc[CH];
    #pragma unroll
    for (int ch = 0; ch < CH; ++ch) acc[ch] = (f4)0.0f;

    #pragma unroll
    for (int i = 0; i < K; ++i) {
        // Depth-1 tap pipeline (RA may sink it at VGPR=64; proven harmless).
        if (i + 1 < K) {
            #pragma unroll
            for (int j = 0; j < K; ++j) {
                tnxt[j] = *(const f4*)(kb + (size_t)((i + 1) * K + j) * (H * W));
            }
        }

        #pragma unroll
        for (int ch = 0; ch < CH; ++ch) {
            // x row segment from LDS: cols w0..w0+7 of x-row (wv+i).
            // byte addr = 16*lane + const -> sequential 16B/lane, conflict-free.
            const float* xr = &xs[ch * CH_FLOATS + (wv + i) * WX + w0];
            f4 xa  = *(const f4*)(xr);
            f4 xcv = *(const f4*)(xr + 4);
            float xsg[8] = {xa.x, xa.y, xa.z, xa.w, xcv.x, xcv.y, xcv.z, xcv.w};

            #pragma unroll
            for (int j = 0; j < K; ++j) {      // static indices only (rule #20)
                acc[ch].x = fmaf(xsg[j + 0], tcur[j].x, acc[ch].x);
                acc[ch].y = fmaf(xsg[j + 1], tcur[j].y, acc[ch].y);
                acc[ch].z = fmaf(xsg[j + 2], tcur[j].z, acc[ch].z);
                acc[ch].w = fmaf(xsg[j + 3], tcur[j].w, acc[ch].w);
            }
        }

        if (i + 1 < K) {
            #pragma unroll
            for (int j = 0; j < K; ++j) tcur[j] = tnxt[j];
        }
    }

    float* ob = out + ((size_t)b * C + c0) * (H * W) + (size_t)h * W + w0;
    #pragma unroll
    for (int ch = 0; ch < CH; ++ch) {
        // nt-store: PROVEN 1.5x win (R20 A/B) — keeps the output stream out of
        // L3 so x+kern stay resident across timed graph replays.
        __builtin_nontemporal_store(acc[ch], (f4*)(ob + (size_t)ch * (H * W)));
    }
}

extern "C" void kernel_launch(void* const* d_in, const int* in_sizes, int n_in,
                              void* d_out, int out_size, void* d_ws, size_t ws_size,
                              hipStream_t stream) {
    const float* x    = (const float*)d_in[0];
    const float* kern = (const float*)d_in[1];
    float*       out  = (float*)d_out;

    dim3 grid(NWG);      // 8192 blocks, 1D; decode + swizzle in-kernel
    dim3 block(256);     // 4 row-slices x 64 lanes
    adaptive_conv_kernel<<<grid, block, 0, stream>>>(x, kern, out);
}